// Round 11
// baseline (190.405 us; speedup 1.0000x reference)
//
#include <hip/hip_runtime.h>
#include <cstdint>
#include <cstddef>

#define BB 16
#define NN 4096
#define CC 80
#define MAXD 100
#define CONF_T 0.5f
#define PER_B (MAXD * 4 + MAXD * CC)   // 8400 output elems per batch
#define NWORDS 64                      // 4096/64 bitmap words
#define BCAP 4096
#define FBCAP 2048
#define SEGSZ 2048

// fl32(inter/uni) > 0.5  <=>  inter > uni*(0.5+2^-25), evaluated EXACTLY in
// fp64 (24x25-bit mantissa product = 49 < 53 bits). Bit-identical to the
// reference's IEEE divide + compare. (verified passing rounds 9-10)
#define IOUC 0x1.000001p-1

// ---- workspace layout (fast path) ----
#define WS_KEYS   0x000000             // [B*N] u64 (og int list overlays)
#define WS_Y1S    0x080000             // [B*N] f32 each
#define WS_X1S    0x0C0000
#define WS_Y2S    0x100000
#define WS_X2S    0x140000
#define WS_ARS    0x180000
#define WS_NLIST  0x1C0000             // [B] int
#define WS_KIDX   0x1C0100             // [B*100] int
#define WS_CNT    0x1C2000             // [B] int
#define WS_NEED   0x200000             // 2 MB

__device__ __forceinline__ float rlf(float v, int l) {
    return __int_as_float(__builtin_amdgcn_readlane(__float_as_int(v), l));
}

// ---------------------------------------------------------------------------
// K1 v3: softmax of (10x)^2, ONE WAVE PER ROW, zero LDS.
// Lane L holds element L; lanes 0..15 also hold element 64+L.
// max: shfl_xor fmax tree (exact op -> order-independent, == serial max).
// sum: numpy pairwise-8 DAG reproduced bit-exactly: lane j accumulates
// e[8i+j] for i=0..9 IN ORDER (bpermute broadcasts), then the exact tree
// ((r0+r1)+(r2+r3))+((r4+r5)+(r6+r7)) via readlanes. score = fl(1/s).
// ---------------------------------------------------------------------------
__global__ __launch_bounds__(256) void k_softmax(const float* __restrict__ cls_in,
                                                 float* __restrict__ probs,
                                                 uint64_t* __restrict__ keys) {
#pragma clang fp contract(off)
    int gw   = (int)((blockIdx.x * 256u + threadIdx.x) >> 6);   // row
    int lane = threadIdx.x & 63;
    const float* row = cls_in + (size_t)gw * CC;

    bool has1 = lane < (CC - 64);          // lanes 0..15: second element
    float x0 = row[lane];
    float x1 = has1 ? row[64 + lane] : 0.0f;
    float y0 = x0 * 10.0f; float z0 = y0 * y0;
    float y1 = x1 * 10.0f; float z1 = y1 * y1;

    float m = has1 ? fmaxf(z0, z1) : z0;
    #pragma unroll
    for (int off = 32; off > 0; off >>= 1) m = fmaxf(m, __shfl_xor(m, off));

    float e0 = expf(z0 - m);
    float e1 = has1 ? expf(z1 - m) : 0.0f;

    // numpy pairwise-8: lane j (=lane&7, replicated 8x) accumulates in i-order
    int j = lane & 7;
    float acc = __shfl(e0, j);                       // i=0: c=j
    #pragma unroll
    for (int i = 1; i < 8; ++i) acc = acc + __shfl(e0, 8 * i + j);   // c=8i+j
    acc = acc + __shfl(e1, j);                       // i=8: c=64+j (slot1 lane j)
    acc = acc + __shfl(e1, 8 + j);                   // i=9: c=72+j (slot1 lane 8+j)

    float r0 = rlf(acc, 0), r1 = rlf(acc, 1), r2 = rlf(acc, 2), r3 = rlf(acc, 3);
    float r4 = rlf(acc, 4), r5 = rlf(acc, 5), r6 = rlf(acc, 6), r7 = rlf(acc, 7);
    float s = ((r0 + r1) + (r2 + r3)) + ((r4 + r5) + (r6 + r7));

    float score = 1.0f / s;                // exact IEEE divide — decides order
    float* pr = probs + (size_t)gw * CC;
    pr[lane] = e0 * score;
    if (has1) pr[64 + lane] = e1 * score;

    if (lane == 0) {
        unsigned n = (unsigned)(gw & (NN - 1));
        keys[gw] = ((uint64_t)__float_as_uint(score) << 32)
                 | (uint64_t)(0xFFFFFFFFu - n);
    }
}

// ---------------------------------------------------------------------------
// K2: partition + RANK-sort of B + fused sorted-corner build (r10, passing).
// ---------------------------------------------------------------------------
__global__ __launch_bounds__(1024) void k_part(uint64_t* keys,
                                               const float* __restrict__ boxes,
                                               float* __restrict__ y1s, float* __restrict__ x1s,
                                               float* __restrict__ y2s, float* __restrict__ x2s,
                                               float* __restrict__ ars,
                                               int* __restrict__ nlist_g) {
#pragma clang fp contract(off)
    __shared__ uint64_t bbuf[BCAP];
    __shared__ int wsumA[16], wsumB[16];

    const int tid = threadIdx.x, lane = tid & 63, wv = tid >> 6;
    const int b = blockIdx.x;
    const uint64_t* kb = keys + (size_t)b * NN;
    int* og = (int*)(keys + (size_t)b * NN);
    size_t bN = (size_t)b * NN;

    uint64_t myk[4]; bool fa[4], fb[4];
    int asum = 0, bsum = 0;
    for (int k = 0; k < 4; ++k) {
        uint64_t key = kb[4 * tid + k]; myk[k] = key;
        unsigned hi = (unsigned)(key >> 32);
        fa[k] = (hi == 0x3F800000u);
        fb[k] = (__uint_as_float(hi) > CONF_T) && !fa[k];
        asum += fa[k] ? 1 : 0; bsum += fb[k] ? 1 : 0;
    }
    int ia = asum, ib = bsum;
    for (int off = 1; off < 64; off <<= 1) {
        int va = __shfl_up(ia, off), vb = __shfl_up(ib, off);
        if (lane >= off) { ia += va; ib += vb; }
    }
    if (lane == 63) { wsumA[wv] = ia; wsumB[wv] = ib; }
    __syncthreads();
    int baseA = 0, baseB = 0, cntA = 0, cntB = 0;
    for (int w2 = 0; w2 < 16; ++w2) {
        if (w2 < wv) { baseA += wsumA[w2]; baseB += wsumB[w2]; }
        cntA += wsumA[w2]; cntB += wsumB[w2];
    }
    int pA = baseA + (ia - asum);
    int pB = baseB + (ib - bsum);
    for (int k = 0; k < 4; ++k) {
        if (fa[k]) og[pA++] = 4 * tid + k;          // stable: idx order
        if (fb[k]) bbuf[pB++] = myk[k];
    }
    __syncthreads();

    // rank sort of B (descending), keys unique: one barrier total
    for (int i = tid; i < cntB; i += 1024) {
        uint64_t ki = bbuf[i];
        int rank = 0;
        for (int j2 = 0; j2 < cntB; ++j2) rank += (bbuf[j2] > ki) ? 1 : 0;
        og[cntA + rank] = (int)(0xFFFFFFFFu - (unsigned)(ki & 0xFFFFFFFFull));
    }
    int nl = cntA + cntB;
    if (tid == 0) nlist_g[b] = nl;
    __syncthreads();

    const float* bxp = boxes + bN * 4;
    for (int i = tid; i < nl; i += 1024) {
        int o = og[i];
        float4 bv = ((const float4*)bxp)[o];
        float y1 = fminf(bv.x, bv.z), y2 = fmaxf(bv.x, bv.z);
        float x1 = fminf(bv.y, bv.w), x2 = fmaxf(bv.y, bv.w);
        y1s[bN + i] = y1; x1s[bN + i] = x1;
        y2s[bN + i] = y2; x2s[bN + i] = x2;
        ars[bN + i] = (y2 - y1) * (x2 - x1);
    }
}

// ---------------------------------------------------------------------------
// K3 v2: filter-first bitmap NMS, READLANE broadcasts (no DS-unit traffic in
// the hot filter loop — round-10's 80 us was the shared DS unit serializing
// 16 waves x 5 ds_bpermute per keep per word). Early-exit ballots added.
// ---------------------------------------------------------------------------
__global__ __launch_bounds__(1024) void k_nms3(const float* __restrict__ y1s, const float* __restrict__ x1s,
                                               const float* __restrict__ y2s, const float* __restrict__ x2s,
                                               const float* __restrict__ ars,
                                               const int* __restrict__ nlist_g,
                                               const uint64_t* __restrict__ keys,  // og overlay
                                               int* __restrict__ kidx_out,
                                               int* __restrict__ cnt_out) {
#pragma clang fp contract(off)
    __shared__ float hy1[NN], hx1[NN], hy2[NN], hx2[NN], har[NN];  // 80 KB
    __shared__ uint64_t live_lds[NWORDS];
    __shared__ uint64_t kill[64];
    __shared__ int cand_s[64];
    __shared__ int kpos[MAXD];
    __shared__ int state_s, kept_s, fk0_s, done_s;

    int b = blockIdx.x;
    int tid = threadIdx.x, lane = tid & 63, wv = tid >> 6;
    int nl = nlist_g[b]; if (nl > NN) nl = NN;
    size_t bN = (size_t)b * NN;

    for (int i = tid; i < NN; i += 1024) {
        bool v = i < nl;
        hy1[i] = v ? y1s[bN + i] : 0.f;
        hx1[i] = v ? x1s[bN + i] : 0.f;
        hy2[i] = v ? y2s[bN + i] : 0.f;
        hx2[i] = v ? x2s[bN + i] : 0.f;
        har[i] = v ? ars[bN + i] : 0.f;
    }
    if (tid < NWORDS) {
        int lo = tid * 64;
        uint64_t m;
        if (nl <= lo) m = 0ull;
        else if (nl >= lo + 64) m = ~0ull;
        else m = (1ull << (nl - lo)) - 1ull;
        live_lds[tid] = m;
    }
    if (tid == 0) { state_s = 0; kept_s = 0; fk0_s = 0; done_s = 0; }

    for (;;) {
        __syncthreads();                               // B1
        // ---- select up to 64 lowest live (wave0) ----
        if (wv == 0) {
            uint64_t lw = live_lds[lane];
            int pc = __popcll(lw);
            int inc = pc;
            for (int off = 1; off < 64; off <<= 1) {
                int v = __shfl_up(inc, off);
                if (lane >= off) inc += v;
            }
            int ex0 = inc - pc;
            int total = __shfl(inc, 63);
            int nc = total < 64 ? total : 64;
            uint64_t t2 = lw; int ex = ex0;
            while (t2 && ex < 64) {
                int bi = __ffsll((unsigned long long)t2) - 1;
                cand_s[ex] = 64 * lane + bi;
                ++ex; t2 &= t2 - 1;
            }
            int ntake = nc - ex0;
            if (ntake < 0) ntake = 0;
            if (ntake > pc) ntake = pc;
            uint64_t lw2 = lw;
            for (int k = 0; k < ntake; ++k) lw2 &= lw2 - 1;
            live_lds[lane] = lw2;
            if (lane == 0) {
                for (int s = nc; s < 64; ++s) cand_s[s] = -1;
                state_s = nc;
            }
        }
        __syncthreads();                               // B2
        int st = state_s;
        if (st <= 0) break;

        // ---- 64x64 intra-batch kill matrix ----
        {
            int cj = cand_s[lane];
            bool jv = cj >= 0;
            int cjx = jv ? cj : 0;
            float jy1 = hy1[cjx], jx1 = hx1[cjx], jy2 = hy2[cjx], jx2 = hx2[cjx], jar = har[cjx];
            #pragma unroll
            for (int r = 0; r < 4; ++r) {
                int t = wv + 16 * r;
                int ct = cand_s[t];
                bool tv = ct >= 0;
                int ctx = tv ? ct : 0;
                float ty1 = hy1[ctx], tx1 = hx1[ctx], ty2 = hy2[ctx], tx2 = hx2[ctx], tar = har[ctx];
                float ih = fmaxf(0.f, fminf(ty2, jy2) - fmaxf(ty1, jy1));
                float iw = fmaxf(0.f, fminf(tx2, jx2) - fmaxf(tx1, jx1));
                float inter = ih * iw;
                float uni = (tar + jar) - inter;
                bool s = tv && jv && (inter > 0.f) && ((double)inter > (double)uni * IOUC);
                uint64_t w = __ballot(s);
                if (lane == 0) kill[t] = w;
            }
        }
        __syncthreads();                               // B3
        // ---- exact greedy 64-slot replay (wave0, register-held kill rows) ----
        if (wv == 0) {
            uint64_t kr = kill[lane];                  // lane j holds row j
            int klo = (int)(kr & 0xFFFFFFFFull), khi = (int)(kr >> 32);
            uint64_t suppressed = 0, keptmask = 0;
            for (int j2 = 0; j2 < st; ++j2) {
                if (!((suppressed >> j2) & 1ull)) {
                    keptmask |= 1ull << j2;
                    uint64_t kj = ((uint64_t)(unsigned)__builtin_amdgcn_readlane(khi, j2) << 32)
                                | (uint64_t)(unsigned)__builtin_amdgcn_readlane(klo, j2);
                    suppressed |= kj;
                }
            }
            int k0 = kept_s;
            if ((keptmask >> lane) & 1ull) {
                int pos = k0 + __popcll(keptmask & ((1ull << lane) - 1ull));
                if (pos < MAXD) kpos[pos] = cand_s[lane];
            }
            int k1 = k0 + __popcll(keptmask);
            if (lane == 0) {
                fk0_s = k0;
                kept_s = k1;
                done_s = (k1 >= MAXD || st < 64) ? 1 : 0;
            }
        }
        __syncthreads();                               // B4
        if (done_s) break;

        // ---- parallel filter vs new keeps: readlane broadcasts (VALU only) ----
        {
            int f0 = fk0_s;
            int f1 = kept_s; if (f1 > MAXD) f1 = MAXD;
            #pragma unroll
            for (int r = 0; r < 4; ++r) {
                int g = wv + 16 * r;                   // word index, wave-uniform
                uint64_t lw = live_lds[g];
                if (!lw) continue;
                int idx = 64 * g + lane;
                bool alive = (lw >> lane) & 1ull;
                float y1 = hy1[idx], x1 = hx1[idx], y2 = hy2[idx], x2 = hx2[idx], ar = har[idx];
                bool sup = false;
                for (int q0 = f0; q0 < f1; q0 += 64) {
                    int qi = q0 + lane;
                    int kp = (qi < f1) ? kpos[qi] : 0;
                    float ky1 = hy1[kp], kx1 = hx1[kp], ky2 = hy2[kp], kx2 = hx2[kp], kar = har[kp];
                    int qn = f1 - q0; if (qn > 64) qn = 64;
                    for (int q = 0; q < qn; ++q) {
                        float qy1 = rlf(ky1, q), qx1 = rlf(kx1, q);
                        float qy2 = rlf(ky2, q), qx2 = rlf(kx2, q);
                        float qar = rlf(kar, q);
                        float ih = fmaxf(0.f, fminf(y2, qy2) - fmaxf(y1, qy1));
                        float iw = fmaxf(0.f, fminf(x2, qx2) - fmaxf(x1, qx1));
                        float inter = ih * iw;
                        float uni = (ar + qar) - inter;
                        sup = sup || (inter > 0.f && (double)inter > (double)uni * IOUC);
                        if ((q & 15) == 15 && !__ballot(alive && !sup)) break;
                    }
                    if (!__ballot(alive && !sup)) break;
                }
                uint64_t bal = __ballot(alive && sup);
                if (lane == 0 && bal) live_lds[g] = lw & ~bal;
            }
        }
    }

    int kt = kept_s; if (kt > MAXD) kt = MAXD;
    const int* og = (const int*)(keys + bN);
    if (tid == 0) cnt_out[b] = kt;
    if (tid < MAXD) kidx_out[b * MAXD + tid] = (tid < kt) ? og[kpos[tid]] : 0;
}

// ---------------------------------------------------------------------------
// K4: wide parallel gather (unchanged).
// ---------------------------------------------------------------------------
__global__ __launch_bounds__(256) void k_gather(const float* __restrict__ boxes,
                                                const float* __restrict__ probs,
                                                const int* __restrict__ kidx,
                                                const int* __restrict__ cnt,
                                                float* __restrict__ out_box,
                                                float* __restrict__ out_cls) {
    int u = blockIdx.x * 256 + threadIdx.x;
    if (u >= BB * PER_B) return;
    int b = u / PER_B;
    int r = u - b * PER_B;
    int count = cnt[b];
    float val = 0.0f;
    if (r < MAXD * 4) {
        int t = r >> 2, e = r & 3;
        if (t < count) {
            int idx = kidx[b * MAXD + t];
            val = boxes[((size_t)b * NN + idx) * 4 + e];
        }
        out_box[(size_t)b * MAXD * 4 + r] = val;
    } else {
        int q = r - MAXD * 4;
        int t = q / CC, c = q - t * CC;
        if (t < count) {
            int idx = kidx[b * MAXD + t];
            val = probs[((size_t)b * NN + idx) * CC + c];
        }
        out_cls[(size_t)b * MAXD * CC + q] = val;
    }
}

// ---------------------------------------------------------------------------
// FALLBACK (ws too small): round-4 fused k_nms — verified passing.
// ---------------------------------------------------------------------------
__global__ __launch_bounds__(1024) void k_nms_fb(uint64_t* keys,
                                                 const float* __restrict__ boxes,
                                                 int* __restrict__ kidx_out,
                                                 int* __restrict__ cnt_out) {
#pragma clang fp contract(off)
    __shared__ float sy1[SEGSZ], sx1[SEGSZ], sy2[SEGSZ], sx2[SEGSZ];
    __shared__ int   soidx[SEGSZ];
    __shared__ uint64_t bbuf[FBCAP];
    __shared__ uint64_t sup[NWORDS];
    __shared__ float ky1[MAXD], kx1[MAXD], ky2[MAXD], kx2[MAXD], kar[MAXD];
    __shared__ int   keptidx[MAXD];
    __shared__ int   wsumA[16], wsumB[16];
    __shared__ int   keptcnt_s, ctrl_s, seg_s;

    const int tid = threadIdx.x, lane = tid & 63, wv = tid >> 6;
    const int b = blockIdx.x;
    const uint64_t* kb = keys + (size_t)b * NN;
    const float* bxp = boxes + (size_t)b * NN * 4;
    int* og = (int*)(keys + (size_t)b * NN);

    uint64_t myk[4]; bool fa[4], fb[4];
    int asum = 0, bsum = 0;
    for (int k = 0; k < 4; ++k) {
        uint64_t key = kb[4 * tid + k]; myk[k] = key;
        unsigned hi = (unsigned)(key >> 32);
        fa[k] = (hi == 0x3F800000u);
        fb[k] = (__uint_as_float(hi) > CONF_T) && !fa[k];
        asum += fa[k] ? 1 : 0; bsum += fb[k] ? 1 : 0;
    }
    int ia = asum, ib = bsum;
    for (int off = 1; off < 64; off <<= 1) {
        int va = __shfl_up(ia, off), vb = __shfl_up(ib, off);
        if (lane >= off) { ia += va; ib += vb; }
    }
    if (lane == 63) { wsumA[wv] = ia; wsumB[wv] = ib; }
    __syncthreads();
    int baseA = 0, baseB = 0, cntA = 0, cntB = 0;
    for (int w2 = 0; w2 < 16; ++w2) {
        if (w2 < wv) { baseA += wsumA[w2]; baseB += wsumB[w2]; }
        cntA += wsumA[w2]; cntB += wsumB[w2];
    }
    int pA = baseA + (ia - asum);
    int pB = baseB + (ib - bsum);
    for (int k = 0; k < 4; ++k) {
        if (fa[k]) og[pA++] = 4 * tid + k;
        if (fb[k]) { if (pB < FBCAP) bbuf[pB] = myk[k]; pB++; }
    }
    int cntBc = cntB < FBCAP ? cntB : FBCAP;
    int nlist = cntA + cntBc;
    if (tid == 0) { keptcnt_s = 0; seg_s = 0; }
    for (int i = tid; i < FBCAP; i += 1024) if (i >= cntB) bbuf[i] = 0;
    __syncthreads();

    for (unsigned k2 = 2; k2 <= FBCAP; k2 <<= 1) {
        for (unsigned j = k2 >> 1; j > 0; j >>= 1) {
            for (unsigned i = tid; i < FBCAP; i += 1024) {
                unsigned p = i ^ j;
                if (p > i) {
                    uint64_t va = bbuf[i], vb = bbuf[p];
                    bool desc = ((i & k2) == 0);
                    if (desc ? (va < vb) : (va > vb)) { bbuf[i] = vb; bbuf[p] = va; }
                }
            }
            __syncthreads();
        }
    }
    for (int i = tid; i < cntBc; i += 1024)
        og[cntA + i] = (int)(0xFFFFFFFFu - (unsigned)(bbuf[i] & 0xFFFFFFFFull));
    if (tid < NWORDS) {
        int lo = tid * 64;
        uint64_t mm;
        if (nlist <= lo) mm = ~0ull;
        else if (nlist >= lo + 64) mm = 0ull;
        else mm = (~0ull) << (nlist - lo);
        sup[tid] = mm;
    }
    __syncthreads();

    for (int i = tid; i < SEGSZ; i += 1024) {
        if (i < nlist) {
            int o = og[i];
            soidx[i] = o;
            const float* bp = bxp + (size_t)o * 4;
            float b0 = bp[0], b1 = bp[1], b2 = bp[2], b3 = bp[3];
            sy1[i] = fminf(b0, b2); sy2[i] = fmaxf(b0, b2);
            sx1[i] = fminf(b1, b3); sx2[i] = fmaxf(b1, b3);
        }
    }
    __syncthreads();

    int curw = 0, segr = 0;
    while (true) {
        if (tid == 0) {
            int code = -1;
            for (;;) {
                int wend = (segr + 1) * (SEGSZ / 64);
                if (curw >= wend) {
                    if (segr == 0 && nlist > SEGSZ) {
                        code = -2; segr = 1; seg_s = 1; curw = SEGSZ / 64;
                    } else code = -1;
                    break;
                }
                uint64_t live = ~sup[curw];
                if (live) {
                    int j = __ffsll((unsigned long long)live) - 1;
                    int sel = curw * 64 + j;
                    int li = sel - segr * SEGSZ;
                    int kc = keptcnt_s;
                    keptidx[kc] = soidx[li];
                    ky1[kc] = sy1[li]; kx1[kc] = sx1[li];
                    ky2[kc] = sy2[li]; kx2[kc] = sx2[li];
                    kar[kc] = (sy2[li] - sy1[li]) * (sx2[li] - sx1[li]);
                    keptcnt_s = kc + 1;
                    sup[curw] |= (1ull << j);
                    code = (kc + 1 >= MAXD) ? -1 : sel;
                    break;
                }
                ++curw;
            }
            ctrl_s = code;
        }
        __syncthreads();
        int c = ctrl_s;
        if (c == -1) break;

        if (c == -2) {
            for (int i = tid; i < SEGSZ; i += 1024) {
                int gi = SEGSZ + i;
                if (gi < nlist) {
                    int o = og[gi];
                    soidx[i] = o;
                    const float* bp = bxp + (size_t)o * 4;
                    float b0 = bp[0], b1 = bp[1], b2 = bp[2], b3 = bp[3];
                    sy1[i] = fminf(b0, b2); sy2[i] = fmaxf(b0, b2);
                    sx1[i] = fminf(b1, b3); sx2[i] = fmaxf(b1, b3);
                }
            }
            __syncthreads();
            int kc = keptcnt_s;
            for (int k = 0; k < 2; ++k) {
                int li = tid + k * 1024;
                float y1 = sy1[li], y2 = sy2[li], x1 = sx1[li], x2 = sx2[li];
                float ar = (y2 - y1) * (x2 - x1);
                bool s = false;
                for (int q = 0; q < kc; ++q) {
                    float ih = fmaxf(0.f, fminf(y2, ky2[q]) - fmaxf(y1, ky1[q]));
                    float iw = fmaxf(0.f, fminf(x2, kx2[q]) - fmaxf(x1, kx1[q]));
                    float inter = ih * iw;
                    float uni = (ar + kar[q]) - inter;
                    s = s || (inter > 0.f && inter / uni > 0.5f);
                }
                uint64_t bal = __ballot(s);
                if (lane == 0 && bal) {
                    int word = (SEGSZ + k * 1024 + wv * 64) >> 6;
                    sup[word] |= bal;
                }
            }
            __syncthreads();
            continue;
        }

        int sg = seg_s;
        int cl = c - sg * SEGSZ;
        float cy1 = sy1[cl], cy2 = sy2[cl], cx1 = sx1[cl], cx2 = sx2[cl];
        float car = (cy2 - cy1) * (cx2 - cx1);
        for (int k = 0; k < 2; ++k) {
            int li = tid + k * 1024;
            float y1 = sy1[li], y2 = sy2[li], x1 = sx1[li], x2 = sx2[li];
            float ar = (y2 - y1) * (x2 - x1);
            float ih = fmaxf(0.f, fminf(y2, cy2) - fmaxf(y1, cy1));
            float iw = fmaxf(0.f, fminf(x2, cx2) - fmaxf(x1, cx1));
            float inter = ih * iw;
            float uni = (ar + car) - inter;
            bool s = (inter > 0.f) && (inter / uni > 0.5f);
            uint64_t bal = __ballot(s);
            if (lane == 0 && bal) {
                int word = (sg * SEGSZ + k * 1024 + wv * 64) >> 6;
                sup[word] |= bal;
            }
        }
        __syncthreads();
    }

    if (tid == 0) cnt_out[b] = keptcnt_s;
    for (int i = tid; i < MAXD; i += 1024)
        kidx_out[b * MAXD + i] = (i < keptcnt_s) ? keptidx[i] : 0;
}

extern "C" void kernel_launch(void* const* d_in, const int* in_sizes, int n_in,
                              void* d_out, int out_size, void* d_ws, size_t ws_size,
                              hipStream_t stream) {
    const float* boxes = (const float*)d_in[0];   // [B,N,4]
    const float* cls   = (const float*)d_in[1];   // [B,N,C]
    float* out = (float*)d_out;
    float* out_box = out;                                                  // [B,100,4]
    float* out_cls = out + (size_t)BB * MAXD * 4;                          // [B,100,80]
    float* probs   = out + (size_t)BB * MAXD * 4 + (size_t)BB * MAXD * CC; // [B,N,80]

    char* ws = (char*)d_ws;
    uint64_t* keys = (uint64_t*)(ws + WS_KEYS);

    k_softmax<<<(BB * NN * 64) / 256, 256, 0, stream>>>(cls, probs, keys);

    if (ws_size >= (size_t)WS_NEED) {
        float* y1s = (float*)(ws + WS_Y1S);
        float* x1s = (float*)(ws + WS_X1S);
        float* y2s = (float*)(ws + WS_Y2S);
        float* x2s = (float*)(ws + WS_X2S);
        float* ars = (float*)(ws + WS_ARS);
        int* nlist = (int*)(ws + WS_NLIST);
        int* kidx  = (int*)(ws + WS_KIDX);
        int* cnt   = (int*)(ws + WS_CNT);

        k_part<<<BB, 1024, 0, stream>>>(keys, boxes, y1s, x1s, y2s, x2s, ars, nlist);
        k_nms3<<<BB, 1024, 0, stream>>>(y1s, x1s, y2s, x2s, ars, nlist,
                                        keys, kidx, cnt);
        k_gather<<<(BB * PER_B + 255) / 256, 256, 0, stream>>>(boxes, probs, kidx, cnt,
                                                               out_box, out_cls);
    } else {
        int* kidx = (int*)(ws + (size_t)BB * NN * sizeof(uint64_t));
        int* cnt  = kidx + BB * MAXD;
        k_nms_fb<<<BB, 1024, 0, stream>>>(keys, boxes, kidx, cnt);
        k_gather<<<(BB * PER_B + 255) / 256, 256, 0, stream>>>(boxes, probs, kidx, cnt,
                                                               out_box, out_cls);
    }
}

// Round 12
// 190.162 us; speedup vs baseline: 1.0013x; 1.0013x over previous
//
#include <hip/hip_runtime.h>
#include <cstdint>
#include <cstddef>

#define BB 16
#define NN 4096
#define CC 80
#define MAXD 100
#define CONF_T 0.5f
#define PER_B (MAXD * 4 + MAXD * CC)   // 8400 output elems per batch
#define NWORDS 64                      // 4096/64 bitmap words
#define BCAP 4096
#define FBCAP 2048
#define SEGSZ 2048

// fl32(inter/uni) > 0.5  <=>  inter > uni*(0.5+2^-25), evaluated EXACTLY in
// fp64 (24x25-bit mantissa product = 49 < 53 bits). Bit-identical to the
// reference's IEEE divide + compare. (verified passing rounds 9-11)
#define IOUC 0x1.000001p-1

// ---- workspace layout (fast path) ----
#define WS_KEYS   0x000000             // [B*N] u64 (og int list overlays)
#define WS_Y1S    0x080000             // [B*N] f32 each
#define WS_X1S    0x0C0000
#define WS_Y2S    0x100000
#define WS_X2S    0x140000
#define WS_ARS    0x180000
#define WS_NLIST  0x1C0000             // [B] int
#define WS_KIDX   0x1C0100             // [B*100] int
#define WS_CNT    0x1C2000             // [B] int
#define WS_KGLB   0x1C4000             // [B*256] float4 keep-corner ring
#define WS_NEED   0x200000             // 2 MB

__device__ __forceinline__ float rlf(float v, int l) {
    return __int_as_float(__builtin_amdgcn_readlane(__float_as_int(v), l));
}

// ---------------------------------------------------------------------------
// K1 v3: softmax of (10x)^2, one wave per row, zero LDS (r11, passing).
// ---------------------------------------------------------------------------
__global__ __launch_bounds__(256) void k_softmax(const float* __restrict__ cls_in,
                                                 float* __restrict__ probs,
                                                 uint64_t* __restrict__ keys) {
#pragma clang fp contract(off)
    int gw   = (int)((blockIdx.x * 256u + threadIdx.x) >> 6);   // row
    int lane = threadIdx.x & 63;
    const float* row = cls_in + (size_t)gw * CC;

    bool has1 = lane < (CC - 64);
    float x0 = row[lane];
    float x1 = has1 ? row[64 + lane] : 0.0f;
    float y0 = x0 * 10.0f; float z0 = y0 * y0;
    float y1 = x1 * 10.0f; float z1 = y1 * y1;

    float m = has1 ? fmaxf(z0, z1) : z0;
    #pragma unroll
    for (int off = 32; off > 0; off >>= 1) m = fmaxf(m, __shfl_xor(m, off));

    float e0 = expf(z0 - m);
    float e1 = has1 ? expf(z1 - m) : 0.0f;

    // numpy pairwise-8 DAG, bit-exact (see r11)
    int j = lane & 7;
    float acc = __shfl(e0, j);
    #pragma unroll
    for (int i = 1; i < 8; ++i) acc = acc + __shfl(e0, 8 * i + j);
    acc = acc + __shfl(e1, j);
    acc = acc + __shfl(e1, 8 + j);

    float r0 = rlf(acc, 0), r1 = rlf(acc, 1), r2 = rlf(acc, 2), r3 = rlf(acc, 3);
    float r4 = rlf(acc, 4), r5 = rlf(acc, 5), r6 = rlf(acc, 6), r7 = rlf(acc, 7);
    float s = ((r0 + r1) + (r2 + r3)) + ((r4 + r5) + (r6 + r7));

    float score = 1.0f / s;
    float* pr = probs + (size_t)gw * CC;
    pr[lane] = e0 * score;
    if (has1) pr[64 + lane] = e1 * score;

    if (lane == 0) {
        unsigned n = (unsigned)(gw & (NN - 1));
        keys[gw] = ((uint64_t)__float_as_uint(score) << 32)
                 | (uint64_t)(0xFFFFFFFFu - n);
    }
}

// ---------------------------------------------------------------------------
// K2: partition + rank-sort of B + fused sorted-corner build (r10, passing).
// ---------------------------------------------------------------------------
__global__ __launch_bounds__(1024) void k_part(uint64_t* keys,
                                               const float* __restrict__ boxes,
                                               float* __restrict__ y1s, float* __restrict__ x1s,
                                               float* __restrict__ y2s, float* __restrict__ x2s,
                                               float* __restrict__ ars,
                                               int* __restrict__ nlist_g) {
#pragma clang fp contract(off)
    __shared__ uint64_t bbuf[BCAP];
    __shared__ int wsumA[16], wsumB[16];

    const int tid = threadIdx.x, lane = tid & 63, wv = tid >> 6;
    const int b = blockIdx.x;
    const uint64_t* kb = keys + (size_t)b * NN;
    int* og = (int*)(keys + (size_t)b * NN);
    size_t bN = (size_t)b * NN;

    uint64_t myk[4]; bool fa[4], fb[4];
    int asum = 0, bsum = 0;
    for (int k = 0; k < 4; ++k) {
        uint64_t key = kb[4 * tid + k]; myk[k] = key;
        unsigned hi = (unsigned)(key >> 32);
        fa[k] = (hi == 0x3F800000u);
        fb[k] = (__uint_as_float(hi) > CONF_T) && !fa[k];
        asum += fa[k] ? 1 : 0; bsum += fb[k] ? 1 : 0;
    }
    int ia = asum, ib = bsum;
    for (int off = 1; off < 64; off <<= 1) {
        int va = __shfl_up(ia, off), vb = __shfl_up(ib, off);
        if (lane >= off) { ia += va; ib += vb; }
    }
    if (lane == 63) { wsumA[wv] = ia; wsumB[wv] = ib; }
    __syncthreads();
    int baseA = 0, baseB = 0, cntA = 0, cntB = 0;
    for (int w2 = 0; w2 < 16; ++w2) {
        if (w2 < wv) { baseA += wsumA[w2]; baseB += wsumB[w2]; }
        cntA += wsumA[w2]; cntB += wsumB[w2];
    }
    int pA = baseA + (ia - asum);
    int pB = baseB + (ib - bsum);
    for (int k = 0; k < 4; ++k) {
        if (fa[k]) og[pA++] = 4 * tid + k;          // stable: idx order
        if (fb[k]) bbuf[pB++] = myk[k];
    }
    __syncthreads();

    // rank sort of B (descending), keys unique
    for (int i = tid; i < cntB; i += 1024) {
        uint64_t ki = bbuf[i];
        int rank = 0;
        for (int j2 = 0; j2 < cntB; ++j2) rank += (bbuf[j2] > ki) ? 1 : 0;
        og[cntA + rank] = (int)(0xFFFFFFFFu - (unsigned)(ki & 0xFFFFFFFFull));
    }
    int nl = cntA + cntB;
    if (tid == 0) nlist_g[b] = nl;
    __syncthreads();

    const float* bxp = boxes + bN * 4;
    for (int i = tid; i < nl; i += 1024) {
        int o = og[i];
        float4 bv = ((const float4*)bxp)[o];
        float y1 = fminf(bv.x, bv.z), y2 = fmaxf(bv.x, bv.z);
        float x1 = fminf(bv.y, bv.w), x2 = fmaxf(bv.y, bv.w);
        y1s[bN + i] = y1; x1s[bN + i] = x1;
        y2s[bN + i] = y2; x2s[bN + i] = x2;
        ars[bN + i] = (y2 - y1) * (x2 - x1);
    }
}

// ---------------------------------------------------------------------------
// K3 v4: filter-first bitmap NMS with L1-BROADCAST keep corners.
// Replay (wave0) stores each new keep's corners as float4 to global kglob;
// the filter reads kglob[q] at a wave-UNIFORM address -> one VMEM L1
// transaction with HW broadcast per keep, ZERO ds_bpermute (rounds 10/11's
// 80-93 us were the DS unit serializing 5 shuffle-broadcasts per pair).
// Addresses f0..f1 are written fresh each round -> no stale-cache hazard.
// ---------------------------------------------------------------------------
__global__ __launch_bounds__(1024) void k_nms3(const float* __restrict__ y1s, const float* __restrict__ x1s,
                                               const float* __restrict__ y2s, const float* __restrict__ x2s,
                                               const float* __restrict__ ars,
                                               const int* __restrict__ nlist_g,
                                               const uint64_t* __restrict__ keys,  // og overlay
                                               float4* kglob_all,
                                               int* __restrict__ kidx_out,
                                               int* __restrict__ cnt_out) {
#pragma clang fp contract(off)
    __shared__ float hy1[NN], hx1[NN], hy2[NN], hx2[NN], har[NN];  // 80 KB
    __shared__ uint64_t live_lds[NWORDS];
    __shared__ uint64_t kill[64];
    __shared__ int cand_s[64];
    __shared__ int kpos[MAXD];
    __shared__ int state_s, kept_s, fk0_s, done_s;

    int b = blockIdx.x;
    int tid = threadIdx.x, lane = tid & 63, wv = tid >> 6;
    int nl = nlist_g[b]; if (nl > NN) nl = NN;
    size_t bN = (size_t)b * NN;
    float4* kglob = kglob_all + b * 256;

    for (int i = tid; i < NN; i += 1024) {
        bool v = i < nl;
        hy1[i] = v ? y1s[bN + i] : 0.f;
        hx1[i] = v ? x1s[bN + i] : 0.f;
        hy2[i] = v ? y2s[bN + i] : 0.f;
        hx2[i] = v ? x2s[bN + i] : 0.f;
        har[i] = v ? ars[bN + i] : 0.f;
    }
    if (tid < NWORDS) {
        int lo = tid * 64;
        uint64_t m;
        if (nl <= lo) m = 0ull;
        else if (nl >= lo + 64) m = ~0ull;
        else m = (1ull << (nl - lo)) - 1ull;
        live_lds[tid] = m;
    }
    if (tid == 0) { state_s = 0; kept_s = 0; fk0_s = 0; done_s = 0; }

    for (;;) {
        __syncthreads();                               // B1
        // ---- select up to 64 lowest live (wave0) ----
        if (wv == 0) {
            uint64_t lw = live_lds[lane];
            int pc = __popcll(lw);
            int inc = pc;
            for (int off = 1; off < 64; off <<= 1) {
                int v = __shfl_up(inc, off);
                if (lane >= off) inc += v;
            }
            int ex0 = inc - pc;
            int total = __shfl(inc, 63);
            int nc = total < 64 ? total : 64;
            uint64_t t2 = lw; int ex = ex0;
            while (t2 && ex < 64) {
                int bi = __ffsll((unsigned long long)t2) - 1;
                cand_s[ex] = 64 * lane + bi;
                ++ex; t2 &= t2 - 1;
            }
            int ntake = nc - ex0;
            if (ntake < 0) ntake = 0;
            if (ntake > pc) ntake = pc;
            uint64_t lw2 = lw;
            for (int k = 0; k < ntake; ++k) lw2 &= lw2 - 1;
            live_lds[lane] = lw2;
            if (lane == 0) {
                for (int s = nc; s < 64; ++s) cand_s[s] = -1;
                state_s = nc;
            }
        }
        __syncthreads();                               // B2
        int st = state_s;
        if (st <= 0) break;

        // ---- 64x64 intra-batch kill matrix ----
        {
            int cj = cand_s[lane];
            bool jv = cj >= 0;
            int cjx = jv ? cj : 0;
            float jy1 = hy1[cjx], jx1 = hx1[cjx], jy2 = hy2[cjx], jx2 = hx2[cjx], jar = har[cjx];
            #pragma unroll
            for (int r = 0; r < 4; ++r) {
                int t = wv + 16 * r;
                int ct = cand_s[t];
                bool tv = ct >= 0;
                int ctx = tv ? ct : 0;
                float ty1 = hy1[ctx], tx1 = hx1[ctx], ty2 = hy2[ctx], tx2 = hx2[ctx], tar = har[ctx];
                float ih = fmaxf(0.f, fminf(ty2, jy2) - fmaxf(ty1, jy1));
                float iw = fmaxf(0.f, fminf(tx2, jx2) - fmaxf(tx1, jx1));
                float inter = ih * iw;
                float uni = (tar + jar) - inter;
                bool s = tv && jv && (inter > 0.f) && ((double)inter > (double)uni * IOUC);
                uint64_t w = __ballot(s);
                if (lane == 0) kill[t] = w;
            }
        }
        __syncthreads();                               // B3
        // ---- exact greedy 64-slot replay (wave0, register kill rows) ----
        if (wv == 0) {
            uint64_t kr = kill[lane];                  // lane j holds row j
            int klo = (int)(kr & 0xFFFFFFFFull), khi = (int)(kr >> 32);
            uint64_t suppressed = 0, keptmask = 0;
            for (int j2 = 0; j2 < st; ++j2) {
                if (!((suppressed >> j2) & 1ull)) {
                    keptmask |= 1ull << j2;
                    uint64_t kj = ((uint64_t)(unsigned)__builtin_amdgcn_readlane(khi, j2) << 32)
                                | (uint64_t)(unsigned)__builtin_amdgcn_readlane(klo, j2);
                    suppressed |= kj;
                }
            }
            int k0 = kept_s;
            if ((keptmask >> lane) & 1ull) {
                int pos = k0 + __popcll(keptmask & ((1ull << lane) - 1ull));
                if (pos < MAXD) {
                    int cc = cand_s[lane];
                    kpos[pos] = cc;
                    kglob[pos] = make_float4(hy1[cc], hx1[cc], hy2[cc], hx2[cc]);
                }
            }
            int k1 = k0 + __popcll(keptmask);
            if (lane == 0) {
                fk0_s = k0;
                kept_s = k1;
                done_s = (k1 >= MAXD || st < 64) ? 1 : 0;
            }
        }
        __syncthreads();                               // B4 (drains wave0 stores)
        if (done_s) break;

        // ---- parallel filter vs new keeps: uniform float4 loads (L1 bcast) ----
        {
            int f0 = fk0_s;
            int f1 = kept_s; if (f1 > MAXD) f1 = MAXD;
            #pragma unroll
            for (int r = 0; r < 4; ++r) {
                int g = wv + 16 * r;                   // word index, wave-uniform
                uint64_t lw = live_lds[g];
                if (!lw) continue;
                int idx = 64 * g + lane;
                bool alive = (lw >> lane) & 1ull;
                float y1 = hy1[idx], x1 = hx1[idx], y2 = hy2[idx], x2 = hx2[idx], ar = har[idx];
                bool sup = false;
                for (int q = f0; q < f1; ++q) {
                    float4 kk = kglob[q];              // uniform addr -> 1 VMEM
                    float qar = (kk.z - kk.x) * (kk.w - kk.y);   // bit-== ars
                    float ih = fmaxf(0.f, fminf(y2, kk.z) - fmaxf(y1, kk.x));
                    float iw = fmaxf(0.f, fminf(x2, kk.w) - fmaxf(x1, kk.y));
                    float inter = ih * iw;
                    float uni = (ar + qar) - inter;
                    sup = sup || (inter > 0.f && (double)inter > (double)uni * IOUC);
                    if (((q - f0) & 7) == 7 && !__ballot(alive && !sup)) break;
                }
                uint64_t bal = __ballot(alive && sup);
                if (lane == 0 && bal) live_lds[g] = lw & ~bal;
            }
        }
    }

    int kt = kept_s; if (kt > MAXD) kt = MAXD;
    const int* og = (const int*)(keys + bN);
    if (tid == 0) cnt_out[b] = kt;
    if (tid < MAXD) kidx_out[b * MAXD + tid] = (tid < kt) ? og[kpos[tid]] : 0;
}

// ---------------------------------------------------------------------------
// K4: wide parallel gather (unchanged).
// ---------------------------------------------------------------------------
__global__ __launch_bounds__(256) void k_gather(const float* __restrict__ boxes,
                                                const float* __restrict__ probs,
                                                const int* __restrict__ kidx,
                                                const int* __restrict__ cnt,
                                                float* __restrict__ out_box,
                                                float* __restrict__ out_cls) {
    int u = blockIdx.x * 256 + threadIdx.x;
    if (u >= BB * PER_B) return;
    int b = u / PER_B;
    int r = u - b * PER_B;
    int count = cnt[b];
    float val = 0.0f;
    if (r < MAXD * 4) {
        int t = r >> 2, e = r & 3;
        if (t < count) {
            int idx = kidx[b * MAXD + t];
            val = boxes[((size_t)b * NN + idx) * 4 + e];
        }
        out_box[(size_t)b * MAXD * 4 + r] = val;
    } else {
        int q = r - MAXD * 4;
        int t = q / CC, c = q - t * CC;
        if (t < count) {
            int idx = kidx[b * MAXD + t];
            val = probs[((size_t)b * NN + idx) * CC + c];
        }
        out_cls[(size_t)b * MAXD * CC + q] = val;
    }
}

// ---------------------------------------------------------------------------
// FALLBACK (ws too small): round-4 fused k_nms — verified passing.
// ---------------------------------------------------------------------------
__global__ __launch_bounds__(1024) void k_nms_fb(uint64_t* keys,
                                                 const float* __restrict__ boxes,
                                                 int* __restrict__ kidx_out,
                                                 int* __restrict__ cnt_out) {
#pragma clang fp contract(off)
    __shared__ float sy1[SEGSZ], sx1[SEGSZ], sy2[SEGSZ], sx2[SEGSZ];
    __shared__ int   soidx[SEGSZ];
    __shared__ uint64_t bbuf[FBCAP];
    __shared__ uint64_t sup[NWORDS];
    __shared__ float ky1[MAXD], kx1[MAXD], ky2[MAXD], kx2[MAXD], kar[MAXD];
    __shared__ int   keptidx[MAXD];
    __shared__ int   wsumA[16], wsumB[16];
    __shared__ int   keptcnt_s, ctrl_s, seg_s;

    const int tid = threadIdx.x, lane = tid & 63, wv = tid >> 6;
    const int b = blockIdx.x;
    const uint64_t* kb = keys + (size_t)b * NN;
    const float* bxp = boxes + (size_t)b * NN * 4;
    int* og = (int*)(keys + (size_t)b * NN);

    uint64_t myk[4]; bool fa[4], fb[4];
    int asum = 0, bsum = 0;
    for (int k = 0; k < 4; ++k) {
        uint64_t key = kb[4 * tid + k]; myk[k] = key;
        unsigned hi = (unsigned)(key >> 32);
        fa[k] = (hi == 0x3F800000u);
        fb[k] = (__uint_as_float(hi) > CONF_T) && !fa[k];
        asum += fa[k] ? 1 : 0; bsum += fb[k] ? 1 : 0;
    }
    int ia = asum, ib = bsum;
    for (int off = 1; off < 64; off <<= 1) {
        int va = __shfl_up(ia, off), vb = __shfl_up(ib, off);
        if (lane >= off) { ia += va; ib += vb; }
    }
    if (lane == 63) { wsumA[wv] = ia; wsumB[wv] = ib; }
    __syncthreads();
    int baseA = 0, baseB = 0, cntA = 0, cntB = 0;
    for (int w2 = 0; w2 < 16; ++w2) {
        if (w2 < wv) { baseA += wsumA[w2]; baseB += wsumB[w2]; }
        cntA += wsumA[w2]; cntB += wsumB[w2];
    }
    int pA = baseA + (ia - asum);
    int pB = baseB + (ib - bsum);
    for (int k = 0; k < 4; ++k) {
        if (fa[k]) og[pA++] = 4 * tid + k;
        if (fb[k]) { if (pB < FBCAP) bbuf[pB] = myk[k]; pB++; }
    }
    int cntBc = cntB < FBCAP ? cntB : FBCAP;
    int nlist = cntA + cntBc;
    if (tid == 0) { keptcnt_s = 0; seg_s = 0; }
    for (int i = tid; i < FBCAP; i += 1024) if (i >= cntB) bbuf[i] = 0;
    __syncthreads();

    for (unsigned k2 = 2; k2 <= FBCAP; k2 <<= 1) {
        for (unsigned j = k2 >> 1; j > 0; j >>= 1) {
            for (unsigned i = tid; i < FBCAP; i += 1024) {
                unsigned p = i ^ j;
                if (p > i) {
                    uint64_t va = bbuf[i], vb = bbuf[p];
                    bool desc = ((i & k2) == 0);
                    if (desc ? (va < vb) : (va > vb)) { bbuf[i] = vb; bbuf[p] = va; }
                }
            }
            __syncthreads();
        }
    }
    for (int i = tid; i < cntBc; i += 1024)
        og[cntA + i] = (int)(0xFFFFFFFFu - (unsigned)(bbuf[i] & 0xFFFFFFFFull));
    if (tid < NWORDS) {
        int lo = tid * 64;
        uint64_t mm;
        if (nlist <= lo) mm = ~0ull;
        else if (nlist >= lo + 64) mm = 0ull;
        else mm = (~0ull) << (nlist - lo);
        sup[tid] = mm;
    }
    __syncthreads();

    for (int i = tid; i < SEGSZ; i += 1024) {
        if (i < nlist) {
            int o = og[i];
            soidx[i] = o;
            const float* bp = bxp + (size_t)o * 4;
            float b0 = bp[0], b1 = bp[1], b2 = bp[2], b3 = bp[3];
            sy1[i] = fminf(b0, b2); sy2[i] = fmaxf(b0, b2);
            sx1[i] = fminf(b1, b3); sx2[i] = fmaxf(b1, b3);
        }
    }
    __syncthreads();

    int curw = 0, segr = 0;
    while (true) {
        if (tid == 0) {
            int code = -1;
            for (;;) {
                int wend = (segr + 1) * (SEGSZ / 64);
                if (curw >= wend) {
                    if (segr == 0 && nlist > SEGSZ) {
                        code = -2; segr = 1; seg_s = 1; curw = SEGSZ / 64;
                    } else code = -1;
                    break;
                }
                uint64_t live = ~sup[curw];
                if (live) {
                    int j = __ffsll((unsigned long long)live) - 1;
                    int sel = curw * 64 + j;
                    int li = sel - segr * SEGSZ;
                    int kc = keptcnt_s;
                    keptidx[kc] = soidx[li];
                    ky1[kc] = sy1[li]; kx1[kc] = sx1[li];
                    ky2[kc] = sy2[li]; kx2[kc] = sx2[li];
                    kar[kc] = (sy2[li] - sy1[li]) * (sx2[li] - sx1[li]);
                    keptcnt_s = kc + 1;
                    sup[curw] |= (1ull << j);
                    code = (kc + 1 >= MAXD) ? -1 : sel;
                    break;
                }
                ++curw;
            }
            ctrl_s = code;
        }
        __syncthreads();
        int c = ctrl_s;
        if (c == -1) break;

        if (c == -2) {
            for (int i = tid; i < SEGSZ; i += 1024) {
                int gi = SEGSZ + i;
                if (gi < nlist) {
                    int o = og[gi];
                    soidx[i] = o;
                    const float* bp = bxp + (size_t)o * 4;
                    float b0 = bp[0], b1 = bp[1], b2 = bp[2], b3 = bp[3];
                    sy1[i] = fminf(b0, b2); sy2[i] = fmaxf(b0, b2);
                    sx1[i] = fminf(b1, b3); sx2[i] = fmaxf(b1, b3);
                }
            }
            __syncthreads();
            int kc = keptcnt_s;
            for (int k = 0; k < 2; ++k) {
                int li = tid + k * 1024;
                float y1 = sy1[li], y2 = sy2[li], x1 = sx1[li], x2 = sx2[li];
                float ar = (y2 - y1) * (x2 - x1);
                bool s = false;
                for (int q = 0; q < kc; ++q) {
                    float ih = fmaxf(0.f, fminf(y2, ky2[q]) - fmaxf(y1, ky1[q]));
                    float iw = fmaxf(0.f, fminf(x2, kx2[q]) - fmaxf(x1, kx1[q]));
                    float inter = ih * iw;
                    float uni = (ar + kar[q]) - inter;
                    s = s || (inter > 0.f && inter / uni > 0.5f);
                }
                uint64_t bal = __ballot(s);
                if (lane == 0 && bal) {
                    int word = (SEGSZ + k * 1024 + wv * 64) >> 6;
                    sup[word] |= bal;
                }
            }
            __syncthreads();
            continue;
        }

        int sg = seg_s;
        int cl = c - sg * SEGSZ;
        float cy1 = sy1[cl], cy2 = sy2[cl], cx1 = sx1[cl], cx2 = sx2[cl];
        float car = (cy2 - cy1) * (cx2 - cx1);
        for (int k = 0; k < 2; ++k) {
            int li = tid + k * 1024;
            float y1 = sy1[li], y2 = sy2[li], x1 = sx1[li], x2 = sx2[li];
            float ar = (y2 - y1) * (x2 - x1);
            float ih = fmaxf(0.f, fminf(y2, cy2) - fmaxf(y1, cy1));
            float iw = fmaxf(0.f, fminf(x2, cx2) - fmaxf(x1, cx1));
            float inter = ih * iw;
            float uni = (ar + car) - inter;
            bool s = (inter > 0.f) && (inter / uni > 0.5f);
            uint64_t bal = __ballot(s);
            if (lane == 0 && bal) {
                int word = (sg * SEGSZ + k * 1024 + wv * 64) >> 6;
                sup[word] |= bal;
            }
        }
        __syncthreads();
    }

    if (tid == 0) cnt_out[b] = keptcnt_s;
    for (int i = tid; i < MAXD; i += 1024)
        kidx_out[b * MAXD + i] = (i < keptcnt_s) ? keptidx[i] : 0;
}

extern "C" void kernel_launch(void* const* d_in, const int* in_sizes, int n_in,
                              void* d_out, int out_size, void* d_ws, size_t ws_size,
                              hipStream_t stream) {
    const float* boxes = (const float*)d_in[0];   // [B,N,4]
    const float* cls   = (const float*)d_in[1];   // [B,N,C]
    float* out = (float*)d_out;
    float* out_box = out;                                                  // [B,100,4]
    float* out_cls = out + (size_t)BB * MAXD * 4;                          // [B,100,80]
    float* probs   = out + (size_t)BB * MAXD * 4 + (size_t)BB * MAXD * CC; // [B,N,80]

    char* ws = (char*)d_ws;
    uint64_t* keys = (uint64_t*)(ws + WS_KEYS);

    k_softmax<<<(BB * NN * 64) / 256, 256, 0, stream>>>(cls, probs, keys);

    if (ws_size >= (size_t)WS_NEED) {
        float* y1s = (float*)(ws + WS_Y1S);
        float* x1s = (float*)(ws + WS_X1S);
        float* y2s = (float*)(ws + WS_Y2S);
        float* x2s = (float*)(ws + WS_X2S);
        float* ars = (float*)(ws + WS_ARS);
        int* nlist = (int*)(ws + WS_NLIST);
        int* kidx  = (int*)(ws + WS_KIDX);
        int* cnt   = (int*)(ws + WS_CNT);
        float4* kglob = (float4*)(ws + WS_KGLB);

        k_part<<<BB, 1024, 0, stream>>>(keys, boxes, y1s, x1s, y2s, x2s, ars, nlist);
        k_nms3<<<BB, 1024, 0, stream>>>(y1s, x1s, y2s, x2s, ars, nlist,
                                        keys, kglob, kidx, cnt);
        k_gather<<<(BB * PER_B + 255) / 256, 256, 0, stream>>>(boxes, probs, kidx, cnt,
                                                               out_box, out_cls);
    } else {
        int* kidx = (int*)(ws + (size_t)BB * NN * sizeof(uint64_t));
        int* cnt  = kidx + BB * MAXD;
        k_nms_fb<<<BB, 1024, 0, stream>>>(keys, boxes, kidx, cnt);
        k_gather<<<(BB * PER_B + 255) / 256, 256, 0, stream>>>(boxes, probs, kidx, cnt,
                                                               out_box, out_cls);
    }
}